// Round 13
// baseline (409.036 us; speedup 1.0000x reference)
//
#include <hip/hip_runtime.h>
#include <hip/hip_bf16.h>

#define DEVI __device__ __forceinline__

typedef float f32x4 __attribute__((ext_vector_type(4)));
typedef __bf16 bfx8 __attribute__((ext_vector_type(8)));

constexpr int NODES = 20000;
constexpr int FIN = 256;
constexpr int HH = 512;

DEVI ushort f2b(float f) {
  uint x = __float_as_uint(f);
  return (ushort)((x + 0x7fffu + ((x >> 16) & 1u)) >> 16);
}

DEVI void async16(const void* g, void* l) {
  __builtin_amdgcn_global_load_lds(
      (const __attribute__((address_space(1))) void*)g,
      (__attribute__((address_space(3))) void*)l, 16, 0, 0);
}

// ---------------- workspace zeroing (rocclr small-fill kernel is ~40us!) ----------------
__global__ void zero_ws(uint4* __restrict__ p, int n16) {
  const int i = blockIdx.x * 256 + threadIdx.x;
  if (i < n16) p[i] = (uint4){0, 0, 0, 0};
}

// ---------------- prep: 4x weight transpose + x->bf16 + edge histogram
//                  + FUSED exclusive scan (last-block-done pattern) ----------------
__global__ __launch_bounds__(256)
void prep(const float* __restrict__ W1, const float* __restrict__ W2,
          const float* __restrict__ W3, const float* __restrict__ W4,
          const float* __restrict__ x, const int* __restrict__ ei,
          ushort* __restrict__ Wt1, ushort* __restrict__ Wt2,
          ushort* __restrict__ Wt3, ushort* __restrict__ Wt4,
          ushort* __restrict__ xb, int* __restrict__ deg,
          int* __restrict__ offs, int* __restrict__ cnt, int E) {
  const int b = blockIdx.x, t = threadIdx.x;
  if (b < 896) {
    __shared__ float tile[32][33];
    const float* W;
    ushort* Wt;
    int K, N, tk, tn;
    if (b < 128) {
      W = W1; Wt = Wt1; K = FIN; N = HH; tk = b & 7; tn = b >> 3;
    } else if (b < 384) {
      W = W2; Wt = Wt2; K = HH; N = HH; const int bb = b - 128; tk = bb & 15; tn = bb >> 4;
    } else if (b < 640) {
      W = W3; Wt = Wt3; K = HH; N = HH; const int bb = b - 384; tk = bb & 15; tn = bb >> 4;
    } else {
      W = W4; Wt = Wt4; K = HH; N = HH; const int bb = b - 640; tk = bb & 15; tn = bb >> 4;
    }
    const int k0 = tk * 32, n0 = tn * 32;
    const int r = t >> 5, c = t & 31;
#pragma unroll
    for (int rr = r; rr < 32; rr += 8)
      tile[rr][c] = W[(size_t)(k0 + rr) * N + n0 + c];
    __syncthreads();
#pragma unroll
    for (int rr = r; rr < 32; rr += 8)
      Wt[(size_t)(n0 + rr) * K + k0 + c] = f2b(tile[c][rr]);
  } else if (b < 5896) {
    const size_t i = ((size_t)(b - 896) * 256 + t) * 4;
    if (i < (size_t)NODES * FIN) {
      const float4 v = *(const float4*)(x + i);
      ushort4 o;
      o.x = f2b(v.x); o.y = f2b(v.y); o.z = f2b(v.z); o.w = f2b(v.w);
      *(ushort4*)(xb + i) = o;
    }
  } else {
    const int e = (b - 5896) * 256 + t;
    if (e < E) atomicAdd(&deg[ei[E + e]], 1);  // dst
  }

  // ---- last-block-done: the final finishing block runs the exclusive scan ----
  __shared__ int lastFlag;
  __shared__ int ps[256];
  __syncthreads();
  if (t == 0) {
    __threadfence();
    lastFlag = (atomicAdd(cnt, 1) == (int)gridDim.x - 1);
  }
  __syncthreads();
  if (lastFlag) {
    const int chunk = (NODES + 255) >> 8;  // 79
    const int s0 = t * chunk;
    const int e0 = min(NODES, s0 + chunk);
    int sum = 0;
    for (int i = s0; i < e0; ++i)
      sum += __hip_atomic_load(&deg[i], __ATOMIC_RELAXED, __HIP_MEMORY_SCOPE_AGENT);
    ps[t] = sum;
    __syncthreads();
    for (int d = 1; d < 256; d <<= 1) {
      int v = (t >= d) ? ps[t - d] : 0;
      __syncthreads();
      ps[t] += v;
      __syncthreads();
    }
    int run = (t == 0) ? 0 : ps[t - 1];
    for (int i = s0; i < e0; ++i) {
      offs[i] = run;
      run += __hip_atomic_load(&deg[i], __ATOMIC_RELAXED, __HIP_MEMORY_SCOPE_AGENT);
    }
    if (t == 255) offs[NODES] = ps[255];
  }
}

__global__ void edge_fill(const int* __restrict__ ei, const int* __restrict__ off,
                          int* __restrict__ cur, int* __restrict__ csr, int E) {
  const int e = blockIdx.x * 256 + threadIdx.x;
  if (e < E) {
    const int dst = ei[E + e];
    const int p = atomicAdd(&cur[dst], 1);
    csr[off[dst] + p] = ei[e];
  }
}

// ---------------- XCD-sliced fused aggregate: A = bf16((1+eps)*h + sum_src h) ----------------
DEVI void unpack_add(uint4 v, float* a) {
  a[0] += __uint_as_float((v.x & 0xffffu) << 16);
  a[1] += __uint_as_float(v.x & 0xffff0000u);
  a[2] += __uint_as_float((v.y & 0xffffu) << 16);
  a[3] += __uint_as_float(v.y & 0xffff0000u);
  a[4] += __uint_as_float((v.z & 0xffffu) << 16);
  a[5] += __uint_as_float(v.z & 0xffff0000u);
  a[6] += __uint_as_float((v.w & 0xffffu) << 16);
  a[7] += __uint_as_float(v.w & 0xffff0000u);
}

template <int C>  // C = 256 (NS=4) or 512 (NS=8)
__global__ __launch_bounds__(256)
void agg_gin(const ushort* __restrict__ h, const int* __restrict__ off,
             const int* __restrict__ csr, const float* __restrict__ eps,
             ushort* __restrict__ A) {
  constexpr int NS = C / 64;
  const int slice = blockIdx.x & (NS - 1);
  const int chunk = blockIdx.x / NS;
  const int node = chunk * 32 + (threadIdx.x >> 3);
  if (node >= NODES) return;
  const int l = threadIdx.x & 7;
  const int col = slice * 64 + l * 8;  // ushort units; 16B per lane
  const ushort* base = h + col;
  const float s = 1.0f + eps[0];
  const int b = off[node], e = off[node + 1];
  float a0[8] = {}, a1[8] = {}, a2[8] = {}, a3[8] = {};
  int i = b;
  for (; i + 3 < e; i += 4) {  // 4 independent L2 misses in flight
    const uint4 v0 = *(const uint4*)(base + (size_t)csr[i] * C);
    const uint4 v1 = *(const uint4*)(base + (size_t)csr[i + 1] * C);
    const uint4 v2 = *(const uint4*)(base + (size_t)csr[i + 2] * C);
    const uint4 v3 = *(const uint4*)(base + (size_t)csr[i + 3] * C);
    unpack_add(v0, a0);
    unpack_add(v1, a1);
    unpack_add(v2, a2);
    unpack_add(v3, a3);
  }
  for (; i < e; ++i) {
    const uint4 v0 = *(const uint4*)(base + (size_t)csr[i] * C);
    unpack_add(v0, a0);
  }
  const uint4 hv = *(const uint4*)(base + (size_t)node * C);
  float self[8] = {};
  unpack_add(hv, self);
  float r[8];
#pragma unroll
  for (int j = 0; j < 8; ++j)
    r[j] = s * self[j] + (a0[j] + a1[j]) + (a2[j] + a3[j]);
  uint4 o;
  o.x = (uint)f2b(r[0]) | ((uint)f2b(r[1]) << 16);
  o.y = (uint)f2b(r[2]) | ((uint)f2b(r[3]) << 16);
  o.z = (uint)f2b(r[4]) | ((uint)f2b(r[5]) << 16);
  o.w = (uint)f2b(r[6]) | ((uint)f2b(r[7]) << 16);
  *(uint4*)(A + (size_t)node * C + col) = o;
}

// ---------------- GEMM: C[M,512] = op(A)[M,K]bf16 * Bt[512,K]^T + bias ----------------
// R12 wave layout (BM=64 x BN=128, 4 waves 2x2, single-buffered, setprio),
// PROBE: BK=128 -> half the K-iterations (4 for K=512), 12 global_load_lds in
// flight per vmcnt(0) drain; LDS 48KB -> 3 blocks/CU (vs 5 at BK=64).
// XOR swizzle: 16 chunks/row, phys chunk = logical chunk ^ (row&7)
//   (ds_read: 16 rows/kg spread over 8 chunk positions = 2-way free).
// Grid: x=bid&7 (XCD), idx=bid>>3; rstrip=x+8*(idx>>2), cblk=idx&3.
// BNA=true: A is bf16 Z [M,512]; y=relu(z*cs+cf) in regs -> ds_write swizzled.
// EPI: 0 = bf16 out, no relu; 1 = bf16 out, relu; 2 = f32 out, relu.
// STATS: column sum/sumsq (pre-relu) atomics into st.
template <int K, int EPI, bool STATS, bool BNA>
__global__ __launch_bounds__(256)
void gemm_bt(const void* __restrict__ Asrc, const ushort* __restrict__ Bt,
             const float* __restrict__ bias, void* __restrict__ Cout,
             float* __restrict__ st, const float* __restrict__ stIn,
             const float* __restrict__ g, const float* __restrict__ be, int M) {
  __shared__ ushort lA[64 * 128];
  __shared__ ushort lB[128 * 128];
  __shared__ float cs[BNA ? HH : 1];
  __shared__ float cf[BNA ? HH : 1];
  const int bid = blockIdx.x;
  const int x = bid & 7;
  const int idx = bid >> 3;
  const int rstrip = x + 8 * (idx >> 2);
  const int cblk = idx & 3;
  if (rstrip >= 313) return;
  const int rowBase = rstrip * 64;
  const int colBase = cblk * 128;

  const int t = threadIdx.x;
  const int lane = t & 63;
  const int w = t >> 6;
  const int wr = w >> 1, wc = w & 1;
  const int fr = lane & 15, kg = lane >> 4;

  if (BNA) {
    const float inv = 1.0f / (float)M;
#pragma unroll
    for (int c = t; c < HH; c += 256) {
      const float mu = stIn[c] * inv;
      const float var = stIn[HH + c] * inv - mu * mu;
      const float rs = rsqrtf(var + 1e-5f);
      const float a = g[c] * rs;
      cs[c] = a;
      cf[c] = be[c] - a * mu;
    }
    __syncthreads();
  }

  // staging geometry: 16 chunks/row; A 1024 slots (4/thread), B 2048 (8/thread)
  int pA[4], clogA[4];
  const ushort* gA[4];
  int pB[8];
  const ushort* gB[8];
#pragma unroll
  for (int i = 0; i < 4; ++i) {
    const int p = t + 256 * i;
    const int rowS = p >> 4;
    clogA[i] = (p & 15) ^ (rowS & 7);
    const int ar = min(rowBase + rowS, M - 1);
    gA[i] = (const ushort*)Asrc + (size_t)ar * K + clogA[i] * 8;
    pA[i] = p * 8;
  }
#pragma unroll
  for (int i = 0; i < 8; ++i) {
    const int p = t + 256 * i;
    const int rowS = p >> 4;
    const int clog = (p & 15) ^ (rowS & 7);
    gB[i] = Bt + (size_t)(colBase + rowS) * K + clog * 8;
    pB[i] = p * 8;
  }

  // fragment LDS offsets (ushort units), swizzled read; s = 32-wide k-sub (0..3)
  int aoff[2][4], boff[4][4];
#pragma unroll
  for (int m = 0; m < 2; ++m) {
#pragma unroll
    for (int s = 0; s < 4; ++s) {
      const int row = wr * 32 + m * 16 + fr;
      aoff[m][s] = row * 128 + (((s * 4 + kg) ^ (row & 7)) * 8);
    }
  }
#pragma unroll
  for (int n = 0; n < 4; ++n) {
#pragma unroll
    for (int s = 0; s < 4; ++s) {
      const int col = wc * 64 + n * 16 + fr;
      boff[n][s] = col * 128 + (((s * 4 + kg) ^ (col & 7)) * 8);
    }
  }

  f32x4 acc[2][4] = {};
  constexpr int NKT = K / 128;

  uint4 zvA, zvB, zvC, zvD;  // BNA: prefetched Z (bf16) for current iter
  auto zload = [&](int kt) {
    const int ko = kt * 128;
    zvA = *(const uint4*)(gA[0] + ko);
    zvB = *(const uint4*)(gA[1] + ko);
    zvC = *(const uint4*)(gA[2] + ko);
    zvD = *(const uint4*)(gA[3] + ko);
  };
  auto ztrans1 = [&](uint4 zv, int i, int kt) {
    const int c0 = kt * 128 + clogA[i] * 8;
    const f32x4 ca = *(const f32x4*)&cs[c0];
    const f32x4 cb = *(const f32x4*)&cs[c0 + 4];
    const f32x4 fa = *(const f32x4*)&cf[c0];
    const f32x4 fb = *(const f32x4*)&cf[c0 + 4];
    float z[8];
    z[0] = __uint_as_float((zv.x & 0xffffu) << 16);
    z[1] = __uint_as_float(zv.x & 0xffff0000u);
    z[2] = __uint_as_float((zv.y & 0xffffu) << 16);
    z[3] = __uint_as_float(zv.y & 0xffff0000u);
    z[4] = __uint_as_float((zv.z & 0xffffu) << 16);
    z[5] = __uint_as_float(zv.z & 0xffff0000u);
    z[6] = __uint_as_float((zv.w & 0xffffu) << 16);
    z[7] = __uint_as_float(zv.w & 0xffff0000u);
    float y[8];
#pragma unroll
    for (int j = 0; j < 4; ++j) {
      y[j]     = fmaxf(z[j]     * ca[j] + fa[j], 0.f);
      y[j + 4] = fmaxf(z[j + 4] * cb[j] + fb[j], 0.f);
    }
    uint4 o;
    o.x = (uint)f2b(y[0]) | ((uint)f2b(y[1]) << 16);
    o.y = (uint)f2b(y[2]) | ((uint)f2b(y[3]) << 16);
    o.z = (uint)f2b(y[4]) | ((uint)f2b(y[5]) << 16);
    o.w = (uint)f2b(y[6]) | ((uint)f2b(y[7]) << 16);
    *(uint4*)&lA[pA[i]] = o;
  };

  if (BNA) zload(0);

  for (int kt = 0; kt < NKT; ++kt) {
    const int ko = kt * 128;
    if (BNA) {
#pragma unroll
      for (int i = 0; i < 8; ++i) async16(gB[i] + ko, &lB[pB[i]]);
      ztrans1(zvA, 0, kt);
      ztrans1(zvB, 1, kt);
      ztrans1(zvC, 2, kt);
      ztrans1(zvD, 3, kt);
    } else {
#pragma unroll
      for (int i = 0; i < 4; ++i) async16(gA[i] + ko, &lA[pA[i]]);
#pragma unroll
      for (int i = 0; i < 8; ++i) async16(gB[i] + ko, &lB[pB[i]]);
    }
    __syncthreads();
    if (BNA && kt + 1 < NKT) zload(kt + 1);  // flies under MFMA phase
    __builtin_amdgcn_s_setprio(1);
#pragma unroll
    for (int s = 0; s < 4; ++s) {
      bfx8 a[2], b[4];
#pragma unroll
      for (int m = 0; m < 2; ++m) a[m] = *(const bfx8*)&lA[aoff[m][s]];
#pragma unroll
      for (int n = 0; n < 4; ++n) b[n] = *(const bfx8*)&lB[boff[n][s]];
#pragma unroll
      for (int m = 0; m < 2; ++m)
#pragma unroll
        for (int n = 0; n < 4; ++n)
          acc[m][n] = __builtin_amdgcn_mfma_f32_16x16x32_bf16(a[m], b[n], acc[m][n], 0, 0, 0);
    }
    __builtin_amdgcn_s_setprio(0);
    __syncthreads();
  }

  float sc_[4] = {}, qc_[4] = {};
#pragma unroll
  for (int m = 0; m < 2; ++m) {
#pragma unroll
    for (int j = 0; j < 4; ++j) {
      const int rr = rowBase + wr * 32 + m * 16 + kg * 4 + j;
      if (rr < M) {
#pragma unroll
        for (int n = 0; n < 4; ++n) {
          const int cc = colBase + wc * 64 + n * 16 + fr;
          float v = acc[m][n][j] + bias[cc];
          if (STATS) { sc_[n] += v; qc_[n] += v * v; }
          if (EPI == 2) {
            ((float*)Cout)[(size_t)rr * HH + cc] = fmaxf(v, 0.0f);
          } else {
            const float vv = (EPI == 1) ? fmaxf(v, 0.0f) : v;
            ((ushort*)Cout)[(size_t)rr * HH + cc] = f2b(vv);
          }
        }
      }
    }
  }
  if (STATS) {
#pragma unroll
    for (int n = 0; n < 4; ++n) {
      float s = sc_[n], q = qc_[n];
      s += __shfl_xor(s, 16, 64); q += __shfl_xor(q, 16, 64);
      s += __shfl_xor(s, 32, 64); q += __shfl_xor(q, 32, 64);
      if (kg == 0) {
        const int cc = colBase + wc * 64 + n * 16 + fr;
        atomicAdd(&st[cc], s);
        atomicAdd(&st[HH + cc], q);
      }
    }
  }
}

extern "C" void kernel_launch(void* const* d_in, const int* in_sizes, int n_in,
                              void* d_out, int out_size, void* d_ws, size_t ws_size,
                              hipStream_t stream) {
  const float* x    = (const float*)d_in[0];
  const int*   ei   = (const int*)d_in[1];
  const float* eps1 = (const float*)d_in[2];
  const float* W1   = (const float*)d_in[3];
  const float* b1   = (const float*)d_in[4];
  const float* g1   = (const float*)d_in[5];
  const float* be1  = (const float*)d_in[6];
  const float* W2   = (const float*)d_in[7];
  const float* b2   = (const float*)d_in[8];
  const float* eps2 = (const float*)d_in[9];
  const float* W3   = (const float*)d_in[10];
  const float* b3   = (const float*)d_in[11];
  const float* g2   = (const float*)d_in[12];
  const float* be2  = (const float*)d_in[13];
  const float* W4   = (const float*)d_in[14];
  const float* b4   = (const float*)d_in[15];
  const int E = in_sizes[1] / 2;

  char* ws = (char*)d_ws;
  size_t off = 0;
  auto alloc = [&](size_t bytes) -> char* {
    char* p = ws + off;
    off += (bytes + 255) & ~(size_t)255;
    return p;
  };
  // zero-region: deg, cur, st1, st2, cnt (one zero_ws kernel)
  const size_t ZB = 2 * (size_t)NODES * 4 + 4 * HH * 4 + 16;  // 168208 B, 16-divisible
  char* zb    = alloc(ZB);
  int* deg    = (int*)zb;
  int* cur    = deg + NODES;
  float* st1  = (float*)(cur + NODES);
  float* st2  = st1 + 2 * HH;
  int* cnt    = (int*)(st2 + 2 * HH);
  int*    offs= (int*)alloc(((size_t)NODES + 1) * 4);
  int*    csr = (int*)alloc((size_t)E * 4);
  ushort* Wt1 = (ushort*)alloc((size_t)FIN * HH * 2);
  ushort* Wt2 = (ushort*)alloc((size_t)HH * HH * 2);
  ushort* Wt3 = (ushort*)alloc((size_t)HH * HH * 2);
  ushort* Wt4 = (ushort*)alloc((size_t)HH * HH * 2);
  ushort* xb  = (ushort*)alloc((size_t)NODES * FIN * 2);
  ushort* Abuf= (ushort*)alloc((size_t)NODES * HH * 2);  // A1/A3 (disjoint lifetimes)
  ushort* Zb  = (ushort*)alloc((size_t)NODES * HH * 2);  // Z1/Z2, bf16 pre-BN
  ushort* H1  = (ushort*)alloc((size_t)NODES * HH * 2);  // layer-1 output, bf16

  const int gemmBlocks = 320 * 4;  // 313 active strips of 64 rows x 4 col-blocks
  const int histBlocks = (E + 255) / 256;
  const int n16 = (int)(ZB / 16);

  zero_ws<<<(n16 + 255) / 256, 256, 0, stream>>>((uint4*)zb, n16);
  prep<<<5896 + histBlocks, 256, 0, stream>>>(W1, W2, W3, W4, x, ei,
                                              Wt1, Wt2, Wt3, Wt4, xb, deg,
                                              offs, cnt, E);
  edge_fill<<<histBlocks, 256, 0, stream>>>(ei, offs, cur, csr, E);

  // ---- layer 1 ----
  agg_gin<FIN><<<(NODES / 32) * 4, 256, 0, stream>>>(xb, offs, csr, eps1, Abuf);
  gemm_bt<FIN, 0, true, false><<<gemmBlocks, 256, 0, stream>>>(
      Abuf, Wt1, b1, Zb, st1, nullptr, nullptr, nullptr, NODES);
  gemm_bt<HH, 1, false, true><<<gemmBlocks, 256, 0, stream>>>(
      Zb, Wt2, b2, H1, nullptr, st1, g1, be1, NODES);

  // ---- layer 2 ----
  agg_gin<HH><<<(NODES / 32) * 8, 256, 0, stream>>>(H1, offs, csr, eps2, Abuf);
  gemm_bt<HH, 0, true, false><<<gemmBlocks, 256, 0, stream>>>(
      Abuf, Wt3, b3, Zb, st2, nullptr, nullptr, nullptr, NODES);
  gemm_bt<HH, 2, false, true><<<gemmBlocks, 256, 0, stream>>>(
      Zb, Wt4, b4, (float*)d_out, nullptr, st2, g2, be2, NODES);
}

// Round 14
// 225.257 us; speedup vs baseline: 1.8159x; 1.8159x over previous
//
#include <hip/hip_runtime.h>
#include <hip/hip_bf16.h>

#define DEVI __device__ __forceinline__

typedef float f32x4 __attribute__((ext_vector_type(4)));
typedef __bf16 bfx8 __attribute__((ext_vector_type(8)));

constexpr int NODES = 20000;
constexpr int FIN = 256;
constexpr int HH = 512;

DEVI ushort f2b(float f) {
  uint x = __float_as_uint(f);
  return (ushort)((x + 0x7fffu + ((x >> 16) & 1u)) >> 16);
}

DEVI void async16(const void* g, void* l) {
  __builtin_amdgcn_global_load_lds(
      (const __attribute__((address_space(1))) void*)g,
      (__attribute__((address_space(3))) void*)l, 16, 0, 0);
}

// ---------------- workspace zeroing (rocclr small-fill kernel is ~40us!) ----------------
__global__ void zero_ws(uint4* __restrict__ p, int n16) {
  const int i = blockIdx.x * 256 + threadIdx.x;
  if (i < n16) p[i] = (uint4){0, 0, 0, 0};
}

// ---------------- prep: 4x weight transpose + x->bf16 + edge histogram ----------------
// (R12 version: NO fused scan. R13's last-block-done __threadfence() in 7146
//  blocks serialized on L2 writebacks -> prep 10us -> 240us. Reverted.)
__global__ __launch_bounds__(256)
void prep(const float* __restrict__ W1, const float* __restrict__ W2,
          const float* __restrict__ W3, const float* __restrict__ W4,
          const float* __restrict__ x, const int* __restrict__ ei,
          ushort* __restrict__ Wt1, ushort* __restrict__ Wt2,
          ushort* __restrict__ Wt3, ushort* __restrict__ Wt4,
          ushort* __restrict__ xb, int* __restrict__ deg, int E) {
  const int b = blockIdx.x, t = threadIdx.x;
  if (b < 896) {
    __shared__ float tile[32][33];
    const float* W;
    ushort* Wt;
    int K, N, tk, tn;
    if (b < 128) {
      W = W1; Wt = Wt1; K = FIN; N = HH; tk = b & 7; tn = b >> 3;
    } else if (b < 384) {
      W = W2; Wt = Wt2; K = HH; N = HH; const int bb = b - 128; tk = bb & 15; tn = bb >> 4;
    } else if (b < 640) {
      W = W3; Wt = Wt3; K = HH; N = HH; const int bb = b - 384; tk = bb & 15; tn = bb >> 4;
    } else {
      W = W4; Wt = Wt4; K = HH; N = HH; const int bb = b - 640; tk = bb & 15; tn = bb >> 4;
    }
    const int k0 = tk * 32, n0 = tn * 32;
    const int r = t >> 5, c = t & 31;
#pragma unroll
    for (int rr = r; rr < 32; rr += 8)
      tile[rr][c] = W[(size_t)(k0 + rr) * N + n0 + c];
    __syncthreads();
#pragma unroll
    for (int rr = r; rr < 32; rr += 8)
      Wt[(size_t)(n0 + rr) * K + k0 + c] = f2b(tile[c][rr]);
  } else if (b < 5896) {
    const size_t i = ((size_t)(b - 896) * 256 + t) * 4;
    if (i < (size_t)NODES * FIN) {
      const float4 v = *(const float4*)(x + i);
      ushort4 o;
      o.x = f2b(v.x); o.y = f2b(v.y); o.z = f2b(v.z); o.w = f2b(v.w);
      *(ushort4*)(xb + i) = o;
    }
  } else {
    const int e = (b - 5896) * 256 + t;
    if (e < E) atomicAdd(&deg[ei[E + e]], 1);  // dst
  }
}

// ---------------- CSR build ----------------
__global__ void ex_scan(const int* __restrict__ deg, int* __restrict__ off, int n) {
  __shared__ int ps[1024];
  const int t = threadIdx.x;
  const int chunk = (n + 1023) >> 10;
  const int s = t * chunk;
  const int e = min(n, s + chunk);
  int sum = 0;
  for (int i = s; i < e; ++i) sum += deg[i];
  ps[t] = sum;
  __syncthreads();
  for (int d = 1; d < 1024; d <<= 1) {
    int v = (t >= d) ? ps[t - d] : 0;
    __syncthreads();
    ps[t] += v;
    __syncthreads();
  }
  int run = (t == 0) ? 0 : ps[t - 1];
  for (int i = s; i < e; ++i) { off[i] = run; run += deg[i]; }
  if (t == 1023) off[n] = ps[1023];
}

__global__ void edge_fill(const int* __restrict__ ei, const int* __restrict__ off,
                          int* __restrict__ cur, int* __restrict__ csr, int E) {
  const int e = blockIdx.x * 256 + threadIdx.x;
  if (e < E) {
    const int dst = ei[E + e];
    const int p = atomicAdd(&cur[dst], 1);
    csr[off[dst] + p] = ei[e];
  }
}

// ---------------- XCD-sliced fused aggregate: A = bf16((1+eps)*h + sum_src h) ----------------
DEVI void unpack_add(uint4 v, float* a) {
  a[0] += __uint_as_float((v.x & 0xffffu) << 16);
  a[1] += __uint_as_float(v.x & 0xffff0000u);
  a[2] += __uint_as_float((v.y & 0xffffu) << 16);
  a[3] += __uint_as_float(v.y & 0xffff0000u);
  a[4] += __uint_as_float((v.z & 0xffffu) << 16);
  a[5] += __uint_as_float(v.z & 0xffff0000u);
  a[6] += __uint_as_float((v.w & 0xffffu) << 16);
  a[7] += __uint_as_float(v.w & 0xffff0000u);
}

template <int C>  // C = 256 (NS=4) or 512 (NS=8)
__global__ __launch_bounds__(256)
void agg_gin(const ushort* __restrict__ h, const int* __restrict__ off,
             const int* __restrict__ csr, const float* __restrict__ eps,
             ushort* __restrict__ A) {
  constexpr int NS = C / 64;
  const int slice = blockIdx.x & (NS - 1);
  const int chunk = blockIdx.x / NS;
  const int node = chunk * 32 + (threadIdx.x >> 3);
  if (node >= NODES) return;
  const int l = threadIdx.x & 7;
  const int col = slice * 64 + l * 8;  // ushort units; 16B per lane
  const ushort* base = h + col;
  const float s = 1.0f + eps[0];
  const int b = off[node], e = off[node + 1];
  float a0[8] = {}, a1[8] = {}, a2[8] = {}, a3[8] = {};
  int i = b;
  for (; i + 3 < e; i += 4) {  // 4 independent L2 misses in flight
    const uint4 v0 = *(const uint4*)(base + (size_t)csr[i] * C);
    const uint4 v1 = *(const uint4*)(base + (size_t)csr[i + 1] * C);
    const uint4 v2 = *(const uint4*)(base + (size_t)csr[i + 2] * C);
    const uint4 v3 = *(const uint4*)(base + (size_t)csr[i + 3] * C);
    unpack_add(v0, a0);
    unpack_add(v1, a1);
    unpack_add(v2, a2);
    unpack_add(v3, a3);
  }
  for (; i < e; ++i) {
    const uint4 v0 = *(const uint4*)(base + (size_t)csr[i] * C);
    unpack_add(v0, a0);
  }
  const uint4 hv = *(const uint4*)(base + (size_t)node * C);
  float self[8] = {};
  unpack_add(hv, self);
  float r[8];
#pragma unroll
  for (int j = 0; j < 8; ++j)
    r[j] = s * self[j] + (a0[j] + a1[j]) + (a2[j] + a3[j]);
  uint4 o;
  o.x = (uint)f2b(r[0]) | ((uint)f2b(r[1]) << 16);
  o.y = (uint)f2b(r[2]) | ((uint)f2b(r[3]) << 16);
  o.z = (uint)f2b(r[4]) | ((uint)f2b(r[5]) << 16);
  o.w = (uint)f2b(r[6]) | ((uint)f2b(r[7]) << 16);
  *(uint4*)(A + (size_t)node * C + col) = o;
}

// ---------------- GEMM: C[M,512] = op(A)[M,K]bf16 * Bt[512,K]^T + bias ----------------
// BK=128 probe (isolated this round): BM=64 x BN=128, 4 waves 2x2,
// single-buffered, setprio; 4 K-iterations for K=512, 12 global_load_lds per
// vmcnt(0) drain; LDS 48KB -> 3 blocks/CU.
// XOR swizzle: 16 chunks/row, phys chunk = logical chunk ^ (row&7).
// Grid: x=bid&7 (XCD), idx=bid>>3; rstrip=x+8*(idx>>2), cblk=idx&3.
// BNA=true: A is bf16 Z [M,512]; y=relu(z*cs+cf) in regs -> ds_write swizzled.
// EPI: 0 = bf16 out, no relu; 1 = bf16 out, relu; 2 = f32 out, relu.
// STATS: column sum/sumsq (pre-relu) atomics into st.
template <int K, int EPI, bool STATS, bool BNA>
__global__ __launch_bounds__(256)
void gemm_bt(const void* __restrict__ Asrc, const ushort* __restrict__ Bt,
             const float* __restrict__ bias, void* __restrict__ Cout,
             float* __restrict__ st, const float* __restrict__ stIn,
             const float* __restrict__ g, const float* __restrict__ be, int M) {
  __shared__ ushort lA[64 * 128];
  __shared__ ushort lB[128 * 128];
  __shared__ float cs[BNA ? HH : 1];
  __shared__ float cf[BNA ? HH : 1];
  const int bid = blockIdx.x;
  const int x = bid & 7;
  const int idx = bid >> 3;
  const int rstrip = x + 8 * (idx >> 2);
  const int cblk = idx & 3;
  if (rstrip >= 313) return;
  const int rowBase = rstrip * 64;
  const int colBase = cblk * 128;

  const int t = threadIdx.x;
  const int lane = t & 63;
  const int w = t >> 6;
  const int wr = w >> 1, wc = w & 1;
  const int fr = lane & 15, kg = lane >> 4;

  if (BNA) {
    const float inv = 1.0f / (float)M;
#pragma unroll
    for (int c = t; c < HH; c += 256) {
      const float mu = stIn[c] * inv;
      const float var = stIn[HH + c] * inv - mu * mu;
      const float rs = rsqrtf(var + 1e-5f);
      const float a = g[c] * rs;
      cs[c] = a;
      cf[c] = be[c] - a * mu;
    }
    __syncthreads();
  }

  // staging geometry: 16 chunks/row; A 1024 slots (4/thread), B 2048 (8/thread)
  int pA[4], clogA[4];
  const ushort* gA[4];
  int pB[8];
  const ushort* gB[8];
#pragma unroll
  for (int i = 0; i < 4; ++i) {
    const int p = t + 256 * i;
    const int rowS = p >> 4;
    clogA[i] = (p & 15) ^ (rowS & 7);
    const int ar = min(rowBase + rowS, M - 1);
    gA[i] = (const ushort*)Asrc + (size_t)ar * K + clogA[i] * 8;
    pA[i] = p * 8;
  }
#pragma unroll
  for (int i = 0; i < 8; ++i) {
    const int p = t + 256 * i;
    const int rowS = p >> 4;
    const int clog = (p & 15) ^ (rowS & 7);
    gB[i] = Bt + (size_t)(colBase + rowS) * K + clog * 8;
    pB[i] = p * 8;
  }

  // fragment LDS offsets (ushort units), swizzled read; s = 32-wide k-sub (0..3)
  int aoff[2][4], boff[4][4];
#pragma unroll
  for (int m = 0; m < 2; ++m) {
#pragma unroll
    for (int s = 0; s < 4; ++s) {
      const int row = wr * 32 + m * 16 + fr;
      aoff[m][s] = row * 128 + (((s * 4 + kg) ^ (row & 7)) * 8);
    }
  }
#pragma unroll
  for (int n = 0; n < 4; ++n) {
#pragma unroll
    for (int s = 0; s < 4; ++s) {
      const int col = wc * 64 + n * 16 + fr;
      boff[n][s] = col * 128 + (((s * 4 + kg) ^ (col & 7)) * 8);
    }
  }

  f32x4 acc[2][4] = {};
  constexpr int NKT = K / 128;

  uint4 zvA, zvB, zvC, zvD;  // BNA: prefetched Z (bf16) for current iter
  auto zload = [&](int kt) {
    const int ko = kt * 128;
    zvA = *(const uint4*)(gA[0] + ko);
    zvB = *(const uint4*)(gA[1] + ko);
    zvC = *(const uint4*)(gA[2] + ko);
    zvD = *(const uint4*)(gA[3] + ko);
  };
  auto ztrans1 = [&](uint4 zv, int i, int kt) {
    const int c0 = kt * 128 + clogA[i] * 8;
    const f32x4 ca = *(const f32x4*)&cs[c0];
    const f32x4 cb = *(const f32x4*)&cs[c0 + 4];
    const f32x4 fa = *(const f32x4*)&cf[c0];
    const f32x4 fb = *(const f32x4*)&cf[c0 + 4];
    float z[8];
    z[0] = __uint_as_float((zv.x & 0xffffu) << 16);
    z[1] = __uint_as_float(zv.x & 0xffff0000u);
    z[2] = __uint_as_float((zv.y & 0xffffu) << 16);
    z[3] = __uint_as_float(zv.y & 0xffff0000u);
    z[4] = __uint_as_float((zv.z & 0xffffu) << 16);
    z[5] = __uint_as_float(zv.z & 0xffff0000u);
    z[6] = __uint_as_float((zv.w & 0xffffu) << 16);
    z[7] = __uint_as_float(zv.w & 0xffff0000u);
    float y[8];
#pragma unroll
    for (int j = 0; j < 4; ++j) {
      y[j]     = fmaxf(z[j]     * ca[j] + fa[j], 0.f);
      y[j + 4] = fmaxf(z[j + 4] * cb[j] + fb[j], 0.f);
    }
    uint4 o;
    o.x = (uint)f2b(y[0]) | ((uint)f2b(y[1]) << 16);
    o.y = (uint)f2b(y[2]) | ((uint)f2b(y[3]) << 16);
    o.z = (uint)f2b(y[4]) | ((uint)f2b(y[5]) << 16);
    o.w = (uint)f2b(y[6]) | ((uint)f2b(y[7]) << 16);
    *(uint4*)&lA[pA[i]] = o;
  };

  if (BNA) zload(0);

  for (int kt = 0; kt < NKT; ++kt) {
    const int ko = kt * 128;
    if (BNA) {
#pragma unroll
      for (int i = 0; i < 8; ++i) async16(gB[i] + ko, &lB[pB[i]]);
      ztrans1(zvA, 0, kt);
      ztrans1(zvB, 1, kt);
      ztrans1(zvC, 2, kt);
      ztrans1(zvD, 3, kt);
    } else {
#pragma unroll
      for (int i = 0; i < 4; ++i) async16(gA[i] + ko, &lA[pA[i]]);
#pragma unroll
      for (int i = 0; i < 8; ++i) async16(gB[i] + ko, &lB[pB[i]]);
    }
    __syncthreads();
    if (BNA && kt + 1 < NKT) zload(kt + 1);  // flies under MFMA phase
    __builtin_amdgcn_s_setprio(1);
#pragma unroll
    for (int s = 0; s < 4; ++s) {
      bfx8 a[2], b[4];
#pragma unroll
      for (int m = 0; m < 2; ++m) a[m] = *(const bfx8*)&lA[aoff[m][s]];
#pragma unroll
      for (int n = 0; n < 4; ++n) b[n] = *(const bfx8*)&lB[boff[n][s]];
#pragma unroll
      for (int m = 0; m < 2; ++m)
#pragma unroll
        for (int n = 0; n < 4; ++n)
          acc[m][n] = __builtin_amdgcn_mfma_f32_16x16x32_bf16(a[m], b[n], acc[m][n], 0, 0, 0);
    }
    __builtin_amdgcn_s_setprio(0);
    __syncthreads();
  }

  float sc_[4] = {}, qc_[4] = {};
#pragma unroll
  for (int m = 0; m < 2; ++m) {
#pragma unroll
    for (int j = 0; j < 4; ++j) {
      const int rr = rowBase + wr * 32 + m * 16 + kg * 4 + j;
      if (rr < M) {
#pragma unroll
        for (int n = 0; n < 4; ++n) {
          const int cc = colBase + wc * 64 + n * 16 + fr;
          float v = acc[m][n][j] + bias[cc];
          if (STATS) { sc_[n] += v; qc_[n] += v * v; }
          if (EPI == 2) {
            ((float*)Cout)[(size_t)rr * HH + cc] = fmaxf(v, 0.0f);
          } else {
            const float vv = (EPI == 1) ? fmaxf(v, 0.0f) : v;
            ((ushort*)Cout)[(size_t)rr * HH + cc] = f2b(vv);
          }
        }
      }
    }
  }
  if (STATS) {
#pragma unroll
    for (int n = 0; n < 4; ++n) {
      float s = sc_[n], q = qc_[n];
      s += __shfl_xor(s, 16, 64); q += __shfl_xor(q, 16, 64);
      s += __shfl_xor(s, 32, 64); q += __shfl_xor(q, 32, 64);
      if (kg == 0) {
        const int cc = colBase + wc * 64 + n * 16 + fr;
        atomicAdd(&st[cc], s);
        atomicAdd(&st[HH + cc], q);
      }
    }
  }
}

extern "C" void kernel_launch(void* const* d_in, const int* in_sizes, int n_in,
                              void* d_out, int out_size, void* d_ws, size_t ws_size,
                              hipStream_t stream) {
  const float* x    = (const float*)d_in[0];
  const int*   ei   = (const int*)d_in[1];
  const float* eps1 = (const float*)d_in[2];
  const float* W1   = (const float*)d_in[3];
  const float* b1   = (const float*)d_in[4];
  const float* g1   = (const float*)d_in[5];
  const float* be1  = (const float*)d_in[6];
  const float* W2   = (const float*)d_in[7];
  const float* b2   = (const float*)d_in[8];
  const float* eps2 = (const float*)d_in[9];
  const float* W3   = (const float*)d_in[10];
  const float* b3   = (const float*)d_in[11];
  const float* g2   = (const float*)d_in[12];
  const float* be2  = (const float*)d_in[13];
  const float* W4   = (const float*)d_in[14];
  const float* b4   = (const float*)d_in[15];
  const int E = in_sizes[1] / 2;

  char* ws = (char*)d_ws;
  size_t off = 0;
  auto alloc = [&](size_t bytes) -> char* {
    char* p = ws + off;
    off += (bytes + 255) & ~(size_t)255;
    return p;
  };
  // zero-region: deg, cur, st1, st2 (one zero_ws kernel)
  const size_t ZB = 2 * (size_t)NODES * 4 + 4 * HH * 4;  // 168192 B, 16-divisible
  char* zb    = alloc(ZB);
  int* deg    = (int*)zb;
  int* cur    = deg + NODES;
  float* st1  = (float*)(cur + NODES);
  float* st2  = st1 + 2 * HH;
  int*    offs= (int*)alloc(((size_t)NODES + 1) * 4);
  int*    csr = (int*)alloc((size_t)E * 4);
  ushort* Wt1 = (ushort*)alloc((size_t)FIN * HH * 2);
  ushort* Wt2 = (ushort*)alloc((size_t)HH * HH * 2);
  ushort* Wt3 = (ushort*)alloc((size_t)HH * HH * 2);
  ushort* Wt4 = (ushort*)alloc((size_t)HH * HH * 2);
  ushort* xb  = (ushort*)alloc((size_t)NODES * FIN * 2);
  ushort* Abuf= (ushort*)alloc((size_t)NODES * HH * 2);  // A1/A3 (disjoint lifetimes)
  ushort* Zb  = (ushort*)alloc((size_t)NODES * HH * 2);  // Z1/Z2, bf16 pre-BN
  ushort* H1  = (ushort*)alloc((size_t)NODES * HH * 2);  // layer-1 output, bf16

  const int gemmBlocks = 320 * 4;  // 313 active strips of 64 rows x 4 col-blocks
  const int histBlocks = (E + 255) / 256;
  const int n16 = (int)(ZB / 16);

  zero_ws<<<(n16 + 255) / 256, 256, 0, stream>>>((uint4*)zb, n16);
  prep<<<5896 + histBlocks, 256, 0, stream>>>(W1, W2, W3, W4, x, ei,
                                              Wt1, Wt2, Wt3, Wt4, xb, deg, E);
  ex_scan<<<1, 1024, 0, stream>>>(deg, offs, NODES);
  edge_fill<<<histBlocks, 256, 0, stream>>>(ei, offs, cur, csr, E);

  // ---- layer 1 ----
  agg_gin<FIN><<<(NODES / 32) * 4, 256, 0, stream>>>(xb, offs, csr, eps1, Abuf);
  gemm_bt<FIN, 0, true, false><<<gemmBlocks, 256, 0, stream>>>(
      Abuf, Wt1, b1, Zb, st1, nullptr, nullptr, nullptr, NODES);
  gemm_bt<HH, 1, false, true><<<gemmBlocks, 256, 0, stream>>>(
      Zb, Wt2, b2, H1, nullptr, st1, g1, be1, NODES);

  // ---- layer 2 ----
  agg_gin<HH><<<(NODES / 32) * 8, 256, 0, stream>>>(H1, offs, csr, eps2, Abuf);
  gemm_bt<HH, 0, true, false><<<gemmBlocks, 256, 0, stream>>>(
      Abuf, Wt3, b3, Zb, st2, nullptr, nullptr, nullptr, NODES);
  gemm_bt<HH, 2, false, true><<<gemmBlocks, 256, 0, stream>>>(
      Zb, Wt4, b4, (float*)d_out, nullptr, st2, g2, be2, NODES);
}